// Round 5
// baseline (129.386 us; speedup 1.0000x reference)
//
#include <hip/hip_runtime.h>

#define B_ 256
#define K_ 10
#define I_ 1152
#define O_ 16
#define C_ 8
#define BKO (B_*K_*O_)   // 40960
#define NX 72            // i0 blocks (uhat grid.x)

static __device__ __forceinline__ unsigned short f32_bf16(float f) {
    unsigned int u = __float_as_uint(f);
    u += 0x7FFFu + ((u >> 16) & 1u);           // round-to-nearest-even
    return (unsigned short)(u >> 16);
}

// DPP butterfly add step (full-rate VALU; ctrl is a compile-time const)
template <int CTRL>
static __device__ __forceinline__ float dpp_add(float v) {
    int x = __builtin_amdgcn_update_dpp(0, __float_as_int(v), CTRL, 0xF, 0xF, true);
    return v + __int_as_float(x);
}
// sum over each 16-lane DPP row: xor1, xor2, half-mirror, mirror
static __device__ __forceinline__ float row16_sum(float v) {
    v = dpp_add<0xB1>(v);     // quad_perm(1,0,3,2)  : + lane^1
    v = dpp_add<0x4E>(v);     // quad_perm(2,3,0,1)  : + lane^2
    v = dpp_add<0x141>(v);    // row_half_mirror     : + other quad
    v = dpp_add<0x140>(v);    // row_mirror          : + other half-row
    return v;
}
// sum over the 4 lanes of each quad (the og group) — VALU-rate, no LDS pipe
static __device__ __forceinline__ float quad4_sum(float v) {
    v = dpp_add<0xB1>(v);     // + lane^1
    v = dpp_add<0x4E>(v);     // + lane^2
    return v;
}

// ---------------------------------------------------------------------------
// uhat_kernel v7 (FROZEN): u[b][k][i][o] = bf16(w·x) + pass-1 partials
// part[x][k][b][o].  grid (72, 4, 10); 256 thr; 4 b per thread.
// ---------------------------------------------------------------------------
__global__ __launch_bounds__(256) void uhat_kernel(
    const float* __restrict__ x, const float* __restrict__ w,
    unsigned short* __restrict__ u, float* __restrict__ part)
{
    __shared__ float w_lds[16 * 132];   // [ii][o*8+c], stride 132: 2-way max
    __shared__ float p_lds[64 * 17];    // [b_local*17 + o], padded rows
    const int t   = threadIdx.x;
    const int i_l = t & 15, tg = t >> 4;
    const int i0  = blockIdx.x * 16;
    const int b0  = blockIdx.y * 64 + tg * 4;
    const int k   = blockIdx.z;
    const int i   = i0 + i_l;
    const bool row_leader = (i_l == 0);

    float4 xr[4][2];
#pragma unroll
    for (int bb = 0; bb < 4; bb++) {
        const float4* xp = (const float4*)(x + ((size_t)(b0 + bb) * I_ + i) * C_);
        xr[bb][0] = xp[0];
        xr[bb][1] = xp[1];
    }

    {
        const float4* ws = (const float4*)(w + ((size_t)k * I_ + i0) * O_ * C_);
#pragma unroll
        for (int r = 0; r < 2; r++) {
            int idx = r * 256 + t;               // float4 index in 16x128 slab
            int ii = idx >> 5, rem = idx & 31;
            *(float4*)&w_lds[ii * 132 + rem * 4] = ws[idx];
        }
    }
    __syncthreads();

    unsigned int pk[4][8];
#pragma unroll
    for (int oo = 0; oo < 8; oo++) {             // o-pair index
        float d[4][2];
#pragma unroll
        for (int h = 0; h < 2; h++) {
            const int o = oo * 2 + h;
            const float4 w0 = *(const float4*)&w_lds[i_l * 132 + o * 8];
            const float4 w1 = *(const float4*)&w_lds[i_l * 132 + o * 8 + 4];
#pragma unroll
            for (int bb = 0; bb < 4; bb++) {
                d[bb][h] = w0.x*xr[bb][0].x + w0.y*xr[bb][0].y
                         + w0.z*xr[bb][0].z + w0.w*xr[bb][0].w
                         + w1.x*xr[bb][1].x + w1.y*xr[bb][1].y
                         + w1.z*xr[bb][1].z + w1.w*xr[bb][1].w;
            }
        }
        // pass-1 fold: i-sum via DPP rows (16 lanes = the 16 i's)
#pragma unroll
        for (int bb = 0; bb < 4; bb++) {
#pragma unroll
            for (int h = 0; h < 2; h++) {
                const float rs = row16_sum(d[bb][h]);
                if (row_leader)
                    p_lds[(tg * 4 + bb) * 17 + oo * 2 + h] = rs;
            }
        }
#pragma unroll
        for (int bb = 0; bb < 4; bb++)
            pk[bb][oo] = (unsigned int)f32_bf16(d[bb][0]) |
                         ((unsigned int)f32_bf16(d[bb][1]) << 16);
    }
    // fused 32 B u store per (b,k,i)
#pragma unroll
    for (int bb = 0; bb < 4; bb++) {
        unsigned int* dst = (unsigned int*)
            (u + (((size_t)(b0 + bb) * K_ + k) * I_ + i) * O_);
        *(uint4*)(dst)     = make_uint4(pk[bb][0], pk[bb][1], pk[bb][2], pk[bb][3]);
        *(uint4*)(dst + 4) = make_uint4(pk[bb][4], pk[bb][5], pk[bb][6], pk[bb][7]);
    }

    // dense partial store: part[x][k][b][o] — wave writes 1024 B contiguous
    __syncthreads();
    {
        const int bl = t >> 2, o4 = (t & 3) * 4;     // b_local, o-quad
        float4 v;
        v.x = p_lds[bl * 17 + o4 + 0];
        v.y = p_lds[bl * 17 + o4 + 1];
        v.z = p_lds[bl * 17 + o4 + 2];
        v.w = p_lds[bl * 17 + o4 + 3];
        *(float4*)&part[(((size_t)blockIdx.x * K_ + k) * 256
                         + blockIdx.y * 64 + bl) * O_ + o4] = v;
    }
}

// ---------------------------------------------------------------------------
// route_all v11: LDS staging via global_load_lds, 3-buffer 2-deep pipeline
// with COUNTED s_waitcnt vmcnt(5) + raw s_barrier (T3/T4).  v10's
// __syncthreads() drained vmcnt(0) every chunk — full HBM latency exposed
// per chunk (42 us @ 31% HBM, 30% VALU = stall-bound).  Invariant: 10 loads
// outstanding at each sync; vmcnt(5) retires exactly the chunk needed next,
// newest 5 stay in flight ACROSS the barrier.  Math bit-identical.
// ---------------------------------------------------------------------------

// one 40 KB chunk: 2560 x 16 B units; 512 thr -> 5 issues/thread; per-wave
// dest = wave-uniform base + lane*16 (global_load_lds constraint).
static __device__ __forceinline__ void stage_chunk(
    const unsigned short* __restrict__ ub0,   // u + b*K*I*O (element ptr)
    int chunk, int t, char* lds_buf)
{
    const int i0 = chunk * 128;
#pragma unroll
    for (int r = 0; r < 5; r++) {
        const int L   = r * 512 + t;          // 16B-unit index in [0,2560)
        const int k   = L >> 8;               // 256 units per k-slab (4 KB)
        const int rem = L & 255;
        const unsigned short* src = ub0 + ((size_t)k * I_ + i0) * O_ + rem * 8;
        char* dst = lds_buf + ((size_t)(r * 512 + (t & ~63)) * 16);
        __builtin_amdgcn_global_load_lds(
            (const __attribute__((address_space(1))) unsigned int*)src,
            (__attribute__((address_space(3))) unsigned int*)dst,
            16, 0, 0);
    }
}

// counted-vmcnt barrier: newest N loads stay in flight across the barrier.
#define PIPE_SYNC(N) do {                                                     \
    asm volatile("s_waitcnt vmcnt(" #N ")" ::: "memory");                     \
    __builtin_amdgcn_s_barrier();                                             \
    asm volatile("" ::: "memory");                                            \
} while (0)

// one chunk's softmax + accumulate from LDS buffer CUR
#define CHUNK(CUR) do {                                                       \
    float c_[K_]; float Z = 0.f;                                              \
    _Pragma("unroll")                                                         \
    for (int k = 0; k < K_; k++) {                                            \
      const uint2 P = *(const uint2*)((CUR) + k * 4096 + boff);               \
      const float f0 = __uint_as_float(P.x << 16);                            \
      const float f1 = __uint_as_float(P.x & 0xffff0000u);                    \
      const float f2 = __uint_as_float(P.y << 16);                            \
      const float f3 = __uint_as_float(P.y & 0xffff0000u);                    \
      float lk = f0*vr[k].x + f1*vr[k].y + f2*vr[k].z + f3*vr[k].w;           \
      lk = quad4_sum(lk);                                                     \
      c_[k] = __expf(lk); Z += c_[k];                                         \
    }                                                                         \
    const float inv = 1.0f / Z;                                               \
    _Pragma("unroll")                                                         \
    for (int k = 0; k < K_; k++) {                                            \
      const uint2 P = *(const uint2*)((CUR) + k * 4096 + boff);               \
      const float ck = c_[k] * inv;                                           \
      acc[k][0] = fmaf(ck, __uint_as_float(P.x << 16),         acc[k][0]);    \
      acc[k][1] = fmaf(ck, __uint_as_float(P.x & 0xffff0000u), acc[k][1]);    \
      acc[k][2] = fmaf(ck, __uint_as_float(P.y << 16),         acc[k][2]);    \
      acc[k][3] = fmaf(ck, __uint_as_float(P.y & 0xffff0000u), acc[k][3]);    \
    }                                                                         \
} while (0)

static __device__ __forceinline__ void sweep_lds(
    const unsigned short* __restrict__ ub0, int t, int i_l, int og,
    const float* __restrict__ v_lds, float acc[K_][4],
    char* __restrict__ buf0, char* __restrict__ buf1, char* __restrict__ buf2)
{
    // v for this thread's o-quad, all k — one aligned ds_read_b128 each
    float4 vr[K_];
#pragma unroll
    for (int k = 0; k < K_; k++)
        vr[k] = *(const float4*)&v_lds[k * 16 + og * 4];

#pragma unroll
    for (int k = 0; k < K_; k++)
#pragma unroll
        for (int j = 0; j < 4; j++) acc[k][j] = 0.f;

    const int boff = i_l * 32 + og * 8;       // byte offset inside a k-slab

    // prologue: chunks 0,1 in flight; wait chunk 0 (5 newest = chunk 1 fly on)
    stage_chunk(ub0, 0, t, buf0);
    stage_chunk(ub0, 1, t, buf1);
    PIPE_SYNC(5);

    // steady state: buffer roles repeat every 3 chunks (j%3)
#pragma unroll 1
    for (int g = 0; g < 2; g++) {
        const int c0 = g * 3;
        stage_chunk(ub0, c0 + 2, t, buf2); CHUNK(buf0); PIPE_SYNC(5);
        stage_chunk(ub0, c0 + 3, t, buf0); CHUNK(buf1); PIPE_SYNC(5);
        stage_chunk(ub0, c0 + 4, t, buf1); CHUNK(buf2); PIPE_SYNC(5);
    }
    // tail: chunks 6,7,8 (stage(8) is the last issue)
    stage_chunk(ub0, 8, t, buf2); CHUNK(buf0); PIPE_SYNC(5);
    CHUNK(buf1); PIPE_SYNC(0);
    CHUNK(buf2);
}

// reduce acc over the 16 i-positions of each wave; deposit per-wave sums.
static __device__ __forceinline__ void block_reduce(
    float acc[K_][4], float* __restrict__ red, int lane, int wv)
{
#pragma unroll
    for (int k = 0; k < K_; k++)
#pragma unroll
        for (int j = 0; j < 4; j++) {
            float a = acc[k][j];
            a += __shfl_xor(a, 4);  a += __shfl_xor(a, 8);
            a += __shfl_xor(a, 16); a += __shfl_xor(a, 32);
            acc[k][j] = a;
        }
    if (lane < 4) {
#pragma unroll
        for (int k = 0; k < K_; k++)
            *(float4*)&red[wv * 160 + k * 16 + lane * 4] =
                make_float4(acc[k][0], acc[k][1], acc[k][2], acc[k][3]);
    }
    __syncthreads();
}

// sum the 8 per-wave partials for element t (t < 160)
static __device__ __forceinline__ float sum8(const float* __restrict__ red, int t)
{
    float s = 0.f;
#pragma unroll
    for (int wgi = 0; wgi < 8; wgi++) s += red[wgi * 160 + t];
    return s;
}

// squash for element t<160: 16-lane o-group norm reduce
static __device__ __forceinline__ float squash_v(float s) {
    float n2 = s * s;
    n2 += __shfl_xor(n2, 1); n2 += __shfl_xor(n2, 2);
    n2 += __shfl_xor(n2, 4); n2 += __shfl_xor(n2, 8);
    const float norm = sqrtf(n2);
    return s * (n2 / (1.0f + n2) / (norm + 1e-9f));
}

// ---------------------------------------------------------------------------
// route_all v11: passes 2+3; pass 1 from part[x][k][b][o].
// grid (256), 512 thr (8 waves).  LDS: 3x40KB u triple-buffer + red + v.
// ---------------------------------------------------------------------------
__global__ __launch_bounds__(512) void route_all(
    const unsigned short* __restrict__ u, const float* __restrict__ part,
    float* __restrict__ out)
{
    __shared__ __align__(16) char ubuf[3][40960];
    __shared__ float red[8 * 160];
    __shared__ float v_lds[160];
    __shared__ float v1_lds[160];

    const int t    = threadIdx.x;
    const int og   = t & 3, i_l = t >> 2;   // og: o-quad, i_l in 0..127
    const int b    = blockIdx.x;
    const int lane = t & 63, wv = t >> 6;

    const unsigned short* ub0 = u + (size_t)b * K_ * I_ * O_;
    float acc[K_][4];

    // ---- prologue: s1 = sum over the 72 i-blocks; v1 = squash(s1/K) ----
    if (t < 160) {
        const int k = t >> 4, o = t & 15;
        const float* pb = part + ((size_t)k * 256 + b) * O_ + o;
        float s = 0.f;
#pragma unroll
        for (int xb = 0; xb < NX; xb++)
            s += pb[(size_t)xb * BKO];
        float v = squash_v(s * (1.0f / K_));
        v1_lds[t] = v;
        v_lds[t]  = v;
    }
    __syncthreads();

    // ---- pass 2: logits from v1 ----
    sweep_lds(ub0, t, i_l, og, v_lds, acc, ubuf[0], ubuf[1], ubuf[2]);
    block_reduce(acc, red, lane, wv);
    float v12 = 0.f;
    if (t < 160) v12 = v1_lds[t] + squash_v(sum8(red, t));
    __syncthreads();          // all sum8 reads done before v_lds overwrite
    if (t < 160) v_lds[t] = v12;
    __syncthreads();

    // ---- pass 3: logits from v1+v2 (telescoped) ----
    sweep_lds(ub0, t, i_l, og, v_lds, acc, ubuf[0], ubuf[1], ubuf[2]);
    block_reduce(acc, red, lane, wv);
    if (t < 160)
        out[(size_t)b * 160 + t] = squash_v(sum8(red, t));
}

// ---------------------------------------------------------------------------
extern "C" void kernel_launch(void* const* d_in, const int* in_sizes, int n_in,
                              void* d_out, int out_size, void* d_ws, size_t ws_size,
                              hipStream_t stream)
{
    const float* x = (const float*)d_in[0];
    const float* w = (const float*)d_in[1];
    float* outp = (float*)d_out;

    float* part = (float*)d_ws;                          // NX*BKO f32 = 11.8 MB
    unsigned short* u = (unsigned short*)(part + (size_t)NX * BKO);  // 94.4 MB

    uhat_kernel<<<dim3(72, 4, 10), 256, 0, stream>>>(x, w, u, part);
    route_all<<<B_, 512, 0, stream>>>(u, part, outp);
}

// Round 7
// 127.243 us; speedup vs baseline: 1.0168x; 1.0168x over previous
//
#include <hip/hip_runtime.h>

#define B_ 256
#define K_ 10
#define I_ 1152
#define O_ 16
#define C_ 8
#define BKO (B_*K_*O_)   // 40960
#define NX 72            // i0 blocks (uhat grid.x)

static __device__ __forceinline__ unsigned short f32_bf16(float f) {
    unsigned int u = __float_as_uint(f);
    u += 0x7FFFu + ((u >> 16) & 1u);           // round-to-nearest-even
    return (unsigned short)(u >> 16);
}

// DPP butterfly add step (full-rate VALU; ctrl is a compile-time const)
template <int CTRL>
static __device__ __forceinline__ float dpp_add(float v) {
    int x = __builtin_amdgcn_update_dpp(0, __float_as_int(v), CTRL, 0xF, 0xF, true);
    return v + __int_as_float(x);
}
// sum over each 16-lane DPP row: xor1, xor2, half-mirror, mirror
static __device__ __forceinline__ float row16_sum(float v) {
    v = dpp_add<0xB1>(v);     // quad_perm(1,0,3,2)  : + lane^1
    v = dpp_add<0x4E>(v);     // quad_perm(2,3,0,1)  : + lane^2
    v = dpp_add<0x141>(v);    // row_half_mirror     : + other quad
    v = dpp_add<0x140>(v);    // row_mirror          : + other half-row
    return v;
}
// sum over the 4 lanes of each quad (the og group) — VALU-rate, no LDS pipe
static __device__ __forceinline__ float quad4_sum(float v) {
    v = dpp_add<0xB1>(v);     // + lane^1
    v = dpp_add<0x4E>(v);     // + lane^2
    return v;
}

// ---------------------------------------------------------------------------
// uhat_kernel v7 (FROZEN): u[b][k][i][o] = bf16(w·x) + pass-1 partials
// part[x][k][b][o].  grid (72, 4, 10); 256 thr; 4 b per thread.
// ---------------------------------------------------------------------------
__global__ __launch_bounds__(256) void uhat_kernel(
    const float* __restrict__ x, const float* __restrict__ w,
    unsigned short* __restrict__ u, float* __restrict__ part)
{
    __shared__ float w_lds[16 * 132];   // [ii][o*8+c], stride 132: 2-way max
    __shared__ float p_lds[64 * 17];    // [b_local*17 + o], padded rows
    const int t   = threadIdx.x;
    const int i_l = t & 15, tg = t >> 4;
    const int i0  = blockIdx.x * 16;
    const int b0  = blockIdx.y * 64 + tg * 4;
    const int k   = blockIdx.z;
    const int i   = i0 + i_l;
    const bool row_leader = (i_l == 0);

    float4 xr[4][2];
#pragma unroll
    for (int bb = 0; bb < 4; bb++) {
        const float4* xp = (const float4*)(x + ((size_t)(b0 + bb) * I_ + i) * C_);
        xr[bb][0] = xp[0];
        xr[bb][1] = xp[1];
    }

    {
        const float4* ws = (const float4*)(w + ((size_t)k * I_ + i0) * O_ * C_);
#pragma unroll
        for (int r = 0; r < 2; r++) {
            int idx = r * 256 + t;               // float4 index in 16x128 slab
            int ii = idx >> 5, rem = idx & 31;
            *(float4*)&w_lds[ii * 132 + rem * 4] = ws[idx];
        }
    }
    __syncthreads();

    unsigned int pk[4][8];
#pragma unroll
    for (int oo = 0; oo < 8; oo++) {             // o-pair index
        float d[4][2];
#pragma unroll
        for (int h = 0; h < 2; h++) {
            const int o = oo * 2 + h;
            const float4 w0 = *(const float4*)&w_lds[i_l * 132 + o * 8];
            const float4 w1 = *(const float4*)&w_lds[i_l * 132 + o * 8 + 4];
#pragma unroll
            for (int bb = 0; bb < 4; bb++) {
                d[bb][h] = w0.x*xr[bb][0].x + w0.y*xr[bb][0].y
                         + w0.z*xr[bb][0].z + w0.w*xr[bb][0].w
                         + w1.x*xr[bb][1].x + w1.y*xr[bb][1].y
                         + w1.z*xr[bb][1].z + w1.w*xr[bb][1].w;
            }
        }
        // pass-1 fold: i-sum via DPP rows (16 lanes = the 16 i's)
#pragma unroll
        for (int bb = 0; bb < 4; bb++) {
#pragma unroll
            for (int h = 0; h < 2; h++) {
                const float rs = row16_sum(d[bb][h]);
                if (row_leader)
                    p_lds[(tg * 4 + bb) * 17 + oo * 2 + h] = rs;
            }
        }
#pragma unroll
        for (int bb = 0; bb < 4; bb++)
            pk[bb][oo] = (unsigned int)f32_bf16(d[bb][0]) |
                         ((unsigned int)f32_bf16(d[bb][1]) << 16);
    }
    // fused 32 B u store per (b,k,i)
#pragma unroll
    for (int bb = 0; bb < 4; bb++) {
        unsigned int* dst = (unsigned int*)
            (u + (((size_t)(b0 + bb) * K_ + k) * I_ + i) * O_);
        *(uint4*)(dst)     = make_uint4(pk[bb][0], pk[bb][1], pk[bb][2], pk[bb][3]);
        *(uint4*)(dst + 4) = make_uint4(pk[bb][4], pk[bb][5], pk[bb][6], pk[bb][7]);
    }

    // dense partial store: part[x][k][b][o] — wave writes 1024 B contiguous
    __syncthreads();
    {
        const int bl = t >> 2, o4 = (t & 3) * 4;     // b_local, o-quad
        float4 v;
        v.x = p_lds[bl * 17 + o4 + 0];
        v.y = p_lds[bl * 17 + o4 + 1];
        v.z = p_lds[bl * 17 + o4 + 2];
        v.w = p_lds[bl * 17 + o4 + 3];
        *(float4*)&part[(((size_t)blockIdx.x * K_ + k) * 256
                         + blockIdx.y * 64 + bl) * O_ + o4] = v;
    }
}

// ---------------------------------------------------------------------------
// route_all v12: counted-vmcnt 3-buffer pipeline, spill-proofed.
// v11's regression was NOT the sync scheme: 6x CHUNK macro expansion pushed
// liveness past the 128-VGPR cap (WRITE_SIZE 160KB -> 8.3MB scratch).  v12
// keeps v10's zero-reg-cache memory pattern (P re-read from LDS; v[k] also
// read from LDS inside the chunk -- broadcast, ~free) and uses a ROLLED
// 7-iter loop with rotating pointers + 2-chunk tail: ONE CHUNK expansion in
// the loop.  Invariant: 10 loads in flight at each PIPE_SYNC(5); the newest
// 5 (next-next chunk) stay in flight across the barrier.  Math bit-identical.
// ---------------------------------------------------------------------------

// one 40 KB chunk: 2560 x 16 B units; 512 thr -> 5 issues/thread; per-wave
// dest = wave-uniform base + lane*16 (global_load_lds constraint).
static __device__ __forceinline__ void stage_chunk(
    const unsigned short* __restrict__ ub0,   // u + b*K*I*O (element ptr)
    int chunk, int t, char* lds_buf)
{
    const int i0 = chunk * 128;
#pragma unroll
    for (int r = 0; r < 5; r++) {
        const int L   = r * 512 + t;          // 16B-unit index in [0,2560)
        const int k   = L >> 8;               // 256 units per k-slab (4 KB)
        const int rem = L & 255;
        const unsigned short* src = ub0 + ((size_t)k * I_ + i0) * O_ + rem * 8;
        char* dst = lds_buf + ((size_t)(r * 512 + (t & ~63)) * 16);
        __builtin_amdgcn_global_load_lds(
            (const __attribute__((address_space(1))) unsigned int*)src,
            (__attribute__((address_space(3))) unsigned int*)dst,
            16, 0, 0);
    }
}

// counted-vmcnt barrier: newest N loads stay in flight across the barrier.
#define PIPE_SYNC(N) do {                                                     \
    asm volatile("s_waitcnt vmcnt(" #N ")" ::: "memory");                     \
    __builtin_amdgcn_s_barrier();                                             \
    asm volatile("" ::: "memory");                                            \
} while (0)

// one chunk's softmax + accumulate from LDS buffer CUR.  v[k] and P both
// come from LDS (no long-lived registers -> no spill pressure).
#define CHUNK(CUR) do {                                                       \
    float c_[K_]; float Z = 0.f;                                              \
    _Pragma("unroll")                                                         \
    for (int k = 0; k < K_; k++) {                                            \
      const uint2 P = *(const uint2*)((CUR) + k * 4096 + boff);               \
      const float4 vk = *(const float4*)&v_lds[k * 16 + voff];                \
      const float f0 = __uint_as_float(P.x << 16);                            \
      const float f1 = __uint_as_float(P.x & 0xffff0000u);                    \
      const float f2 = __uint_as_float(P.y << 16);                            \
      const float f3 = __uint_as_float(P.y & 0xffff0000u);                    \
      float lk = f0*vk.x + f1*vk.y + f2*vk.z + f3*vk.w;                       \
      lk = quad4_sum(lk);                                                     \
      c_[k] = __expf(lk); Z += c_[k];                                         \
    }                                                                         \
    const float inv = 1.0f / Z;                                               \
    _Pragma("unroll")                                                         \
    for (int k = 0; k < K_; k++) {                                            \
      const uint2 P = *(const uint2*)((CUR) + k * 4096 + boff);               \
      const float ck = c_[k] * inv;                                           \
      acc[k][0] = fmaf(ck, __uint_as_float(P.x << 16),         acc[k][0]);    \
      acc[k][1] = fmaf(ck, __uint_as_float(P.x & 0xffff0000u), acc[k][1]);    \
      acc[k][2] = fmaf(ck, __uint_as_float(P.y << 16),         acc[k][2]);    \
      acc[k][3] = fmaf(ck, __uint_as_float(P.y & 0xffff0000u), acc[k][3]);    \
    }                                                                         \
} while (0)

static __device__ __forceinline__ void sweep_lds(
    const unsigned short* __restrict__ ub0, int t, int i_l, int og,
    const float* __restrict__ v_lds, float acc[K_][4],
    char* __restrict__ buf0, char* __restrict__ buf1, char* __restrict__ buf2)
{
#pragma unroll
    for (int k = 0; k < K_; k++)
#pragma unroll
        for (int j = 0; j < 4; j++) acc[k][j] = 0.f;

    const int boff = i_l * 32 + og * 8;       // byte offset inside a k-slab
    const int voff = og * 4;                  // float offset into v row

    // prologue: chunks 0,1 in flight; wait chunk 0 (chunk 1 flies on)
    stage_chunk(ub0, 0, t, buf0);
    stage_chunk(ub0, 1, t, buf1);
    PIPE_SYNC(5);

    // rolled steady state: compute cA (=chunk j), cB in flight (j+1),
    // stage j+2 into cC.  One CHUNK expansion only.
    char* cA = buf0; char* cB = buf1; char* cC = buf2;
#pragma unroll 1
    for (int j = 0; j < 7; j++) {
        stage_chunk(ub0, j + 2, t, cC);       // now 10 outstanding
        CHUNK(cA);
        PIPE_SYNC(5);                         // retire chunk j+1; j+2 in flight
        char* tmp = cA; cA = cB; cB = cC; cC = tmp;
    }
    // tail: cA = chunk 7 (complete), cB = chunk 8 (in flight)
    CHUNK(cA);
    PIPE_SYNC(0);                             // drain chunk 8
    CHUNK(cB);
}

// reduce acc over the 16 i-positions of each wave; deposit per-wave sums.
static __device__ __forceinline__ void block_reduce(
    float acc[K_][4], float* __restrict__ red, int lane, int wv)
{
#pragma unroll
    for (int k = 0; k < K_; k++)
#pragma unroll
        for (int j = 0; j < 4; j++) {
            float a = acc[k][j];
            a += __shfl_xor(a, 4);  a += __shfl_xor(a, 8);
            a += __shfl_xor(a, 16); a += __shfl_xor(a, 32);
            acc[k][j] = a;
        }
    if (lane < 4) {
#pragma unroll
        for (int k = 0; k < K_; k++)
            *(float4*)&red[wv * 160 + k * 16 + lane * 4] =
                make_float4(acc[k][0], acc[k][1], acc[k][2], acc[k][3]);
    }
    __syncthreads();
}

// sum the 8 per-wave partials for element t (t < 160)
static __device__ __forceinline__ float sum8(const float* __restrict__ red, int t)
{
    float s = 0.f;
#pragma unroll
    for (int wgi = 0; wgi < 8; wgi++) s += red[wgi * 160 + t];
    return s;
}

// squash for element t<160: 16-lane o-group norm reduce
static __device__ __forceinline__ float squash_v(float s) {
    float n2 = s * s;
    n2 += __shfl_xor(n2, 1); n2 += __shfl_xor(n2, 2);
    n2 += __shfl_xor(n2, 4); n2 += __shfl_xor(n2, 8);
    const float norm = sqrtf(n2);
    return s * (n2 / (1.0f + n2) / (norm + 1e-9f));
}

// ---------------------------------------------------------------------------
// route_all v12: passes 2+3; pass 1 from part[x][k][b][o].
// grid (256), 512 thr (8 waves).  LDS: 3x40KB u triple-buffer + red + v.
// ---------------------------------------------------------------------------
__global__ __launch_bounds__(512) void route_all(
    const unsigned short* __restrict__ u, const float* __restrict__ part,
    float* __restrict__ out)
{
    __shared__ __align__(16) char ubuf[3][40960];
    __shared__ float red[8 * 160];
    __shared__ float v_lds[160];
    __shared__ float v1_lds[160];

    const int t    = threadIdx.x;
    const int og   = t & 3, i_l = t >> 2;   // og: o-quad, i_l in 0..127
    const int b    = blockIdx.x;
    const int lane = t & 63, wv = t >> 6;

    const unsigned short* ub0 = u + (size_t)b * K_ * I_ * O_;
    float acc[K_][4];

    // ---- prologue: s1 = sum over the 72 i-blocks; v1 = squash(s1/K) ----
    if (t < 160) {
        const int k = t >> 4, o = t & 15;
        const float* pb = part + ((size_t)k * 256 + b) * O_ + o;
        float s = 0.f;
#pragma unroll
        for (int xb = 0; xb < NX; xb++)
            s += pb[(size_t)xb * BKO];
        float v = squash_v(s * (1.0f / K_));
        v1_lds[t] = v;
        v_lds[t]  = v;
    }
    __syncthreads();

    // ---- pass 2: logits from v1 ----
    sweep_lds(ub0, t, i_l, og, v_lds, acc, ubuf[0], ubuf[1], ubuf[2]);
    block_reduce(acc, red, lane, wv);
    float v12 = 0.f;
    if (t < 160) v12 = v1_lds[t] + squash_v(sum8(red, t));
    __syncthreads();          // all sum8 reads done before v_lds overwrite
    if (t < 160) v_lds[t] = v12;
    __syncthreads();

    // ---- pass 3: logits from v1+v2 (telescoped) ----
    sweep_lds(ub0, t, i_l, og, v_lds, acc, ubuf[0], ubuf[1], ubuf[2]);
    block_reduce(acc, red, lane, wv);
    if (t < 160)
        out[(size_t)b * 160 + t] = squash_v(sum8(red, t));
}

// ---------------------------------------------------------------------------
extern "C" void kernel_launch(void* const* d_in, const int* in_sizes, int n_in,
                              void* d_out, int out_size, void* d_ws, size_t ws_size,
                              hipStream_t stream)
{
    const float* x = (const float*)d_in[0];
    const float* w = (const float*)d_in[1];
    float* outp = (float*)d_out;

    float* part = (float*)d_ws;                          // NX*BKO f32 = 11.8 MB
    unsigned short* u = (unsigned short*)(part + (size_t)NX * BKO);  // 94.4 MB

    uhat_kernel<<<dim3(72, 4, 10), 256, 0, stream>>>(x, w, u, part);
    route_all<<<B_, 512, 0, stream>>>(u, part, outp);
}

// Round 8
// 123.128 us; speedup vs baseline: 1.0508x; 1.0334x over previous
//
#include <hip/hip_runtime.h>

#define B_ 256
#define K_ 10
#define I_ 1152
#define O_ 16
#define C_ 8
#define BKO (B_*K_*O_)   // 40960
#define NX 72            // i0 blocks (uhat grid.x)

static __device__ __forceinline__ unsigned short f32_bf16(float f) {
    unsigned int u = __float_as_uint(f);
    u += 0x7FFFu + ((u >> 16) & 1u);           // round-to-nearest-even
    return (unsigned short)(u >> 16);
}

// DPP butterfly add step (full-rate VALU; ctrl is a compile-time const)
template <int CTRL>
static __device__ __forceinline__ float dpp_add(float v) {
    int x = __builtin_amdgcn_update_dpp(0, __float_as_int(v), CTRL, 0xF, 0xF, true);
    return v + __int_as_float(x);
}
// sum over each 16-lane DPP row: xor1, xor2, half-mirror, mirror
static __device__ __forceinline__ float row16_sum(float v) {
    v = dpp_add<0xB1>(v);     // quad_perm(1,0,3,2)  : + lane^1
    v = dpp_add<0x4E>(v);     // quad_perm(2,3,0,1)  : + lane^2
    v = dpp_add<0x141>(v);    // row_half_mirror     : + other quad
    v = dpp_add<0x140>(v);    // row_mirror          : + other half-row
    return v;
}
// sum over 8 consecutive lanes (one i, og=0..7): quad sum + mirrored quad
static __device__ __forceinline__ float quad8_sum(float v) {
    v = dpp_add<0xB1>(v);     // + lane^1
    v = dpp_add<0x4E>(v);     // + lane^2
    v = dpp_add<0x141>(v);    // row_half_mirror: + other quad of the 8
    return v;
}

// ---------------------------------------------------------------------------
// uhat_kernel v7 (FROZEN): u[b][k][i][o] = bf16(w·x) + pass-1 partials
// part[x][k][b][o].  grid (72, 4, 10); 256 thr; 4 b per thread.
// ---------------------------------------------------------------------------
__global__ __launch_bounds__(256) void uhat_kernel(
    const float* __restrict__ x, const float* __restrict__ w,
    unsigned short* __restrict__ u, float* __restrict__ part)
{
    __shared__ float w_lds[16 * 132];   // [ii][o*8+c], stride 132: 2-way max
    __shared__ float p_lds[64 * 17];    // [b_local*17 + o], padded rows
    const int t   = threadIdx.x;
    const int i_l = t & 15, tg = t >> 4;
    const int i0  = blockIdx.x * 16;
    const int b0  = blockIdx.y * 64 + tg * 4;
    const int k   = blockIdx.z;
    const int i   = i0 + i_l;
    const bool row_leader = (i_l == 0);

    float4 xr[4][2];
#pragma unroll
    for (int bb = 0; bb < 4; bb++) {
        const float4* xp = (const float4*)(x + ((size_t)(b0 + bb) * I_ + i) * C_);
        xr[bb][0] = xp[0];
        xr[bb][1] = xp[1];
    }

    {
        const float4* ws = (const float4*)(w + ((size_t)k * I_ + i0) * O_ * C_);
#pragma unroll
        for (int r = 0; r < 2; r++) {
            int idx = r * 256 + t;               // float4 index in 16x128 slab
            int ii = idx >> 5, rem = idx & 31;
            *(float4*)&w_lds[ii * 132 + rem * 4] = ws[idx];
        }
    }
    __syncthreads();

    unsigned int pk[4][8];
#pragma unroll
    for (int oo = 0; oo < 8; oo++) {             // o-pair index
        float d[4][2];
#pragma unroll
        for (int h = 0; h < 2; h++) {
            const int o = oo * 2 + h;
            const float4 w0 = *(const float4*)&w_lds[i_l * 132 + o * 8];
            const float4 w1 = *(const float4*)&w_lds[i_l * 132 + o * 8 + 4];
#pragma unroll
            for (int bb = 0; bb < 4; bb++) {
                d[bb][h] = w0.x*xr[bb][0].x + w0.y*xr[bb][0].y
                         + w0.z*xr[bb][0].z + w0.w*xr[bb][0].w
                         + w1.x*xr[bb][1].x + w1.y*xr[bb][1].y
                         + w1.z*xr[bb][1].z + w1.w*xr[bb][1].w;
            }
        }
        // pass-1 fold: i-sum via DPP rows (16 lanes = the 16 i's)
#pragma unroll
        for (int bb = 0; bb < 4; bb++) {
#pragma unroll
            for (int h = 0; h < 2; h++) {
                const float rs = row16_sum(d[bb][h]);
                if (row_leader)
                    p_lds[(tg * 4 + bb) * 17 + oo * 2 + h] = rs;
            }
        }
#pragma unroll
        for (int bb = 0; bb < 4; bb++)
            pk[bb][oo] = (unsigned int)f32_bf16(d[bb][0]) |
                         ((unsigned int)f32_bf16(d[bb][1]) << 16);
    }
    // fused 32 B u store per (b,k,i)
#pragma unroll
    for (int bb = 0; bb < 4; bb++) {
        unsigned int* dst = (unsigned int*)
            (u + (((size_t)(b0 + bb) * K_ + k) * I_ + i) * O_);
        *(uint4*)(dst)     = make_uint4(pk[bb][0], pk[bb][1], pk[bb][2], pk[bb][3]);
        *(uint4*)(dst + 4) = make_uint4(pk[bb][4], pk[bb][5], pk[bb][6], pk[bb][7]);
    }

    // dense partial store: part[x][k][b][o] — wave writes 1024 B contiguous
    __syncthreads();
    {
        const int bl = t >> 2, o4 = (t & 3) * 4;     // b_local, o-quad
        float4 v;
        v.x = p_lds[bl * 17 + o4 + 0];
        v.y = p_lds[bl * 17 + o4 + 1];
        v.z = p_lds[bl * 17 + o4 + 2];
        v.w = p_lds[bl * 17 + o4 + 3];
        *(float4*)&part[(((size_t)blockIdx.x * K_ + k) * 256
                         + blockIdx.y * 64 + bl) * O_ + o4] = v;
    }
}

// ---------------------------------------------------------------------------
// route_all v13: TLP attack.  v8/v10/v12 (three different schedules) all
// landed at 41-44 us -> not schedule-bound but LATENCY-bound at 2 waves/SIMD
// (1 block/CU, 8 waves, Occupancy 19%).  v13: 1024 threads = 16 waves =
// 4 waves/SIMD, same 256-block grid.  Per-thread o-width halves (og = t&7,
// o-pair, 4 B dword u loads; 8 i x 32 B = 256 B contiguous per wave per k).
// Barrier-free register sweep (v8 style, 1-deep P/Q prefetch): live set
// P[10]+Q[10]+acc[10][2] ~= 65 VGPR, far under the 128 cap a 1024-thr
// block imposes.  o-sum = 8-lane DPP reduce (quad + half-mirror).
// ---------------------------------------------------------------------------
static __device__ __forceinline__ void sweep(
    const char* __restrict__ ubb,   // byte ptr: u + b*K*I*O elements
    int i_l, int og, const float* __restrict__ v_lds, float acc[K_][2])
{
#pragma unroll
    for (int k = 0; k < K_; k++) { acc[k][0] = 0.f; acc[k][1] = 0.f; }

    const int base = i_l * 32 + og * 4;       // bytes within (k, chunk) slab

    unsigned int P[K_], Q[K_];
#pragma unroll
    for (int k = 0; k < K_; k++)
        P[k] = *(const unsigned int*)(ubb + k * 36864 + base);

#pragma unroll 1
    for (int ic = 0; ic < 9; ic++) {
        if (ic + 1 < 9) {
#pragma unroll
            for (int k = 0; k < K_; k++)
                Q[k] = *(const unsigned int*)
                    (ubb + k * 36864 + (ic + 1) * 4096 + base);
        }
        float c_[K_];
        float Z = 0.f;
#pragma unroll
        for (int k = 0; k < K_; k++) {
            const float f0 = __uint_as_float(P[k] << 16);
            const float f1 = __uint_as_float(P[k] & 0xffff0000u);
            const float2 vk = *(const float2*)&v_lds[k * 16 + og * 2];
            float lk = f0 * vk.x + f1 * vk.y;
            lk = quad8_sum(lk);               // o-sum across 8 og lanes
            c_[k] = __expf(lk); Z += c_[k];
        }
        const float inv = 1.0f / Z;
#pragma unroll
        for (int k = 0; k < K_; k++) {
            const float ck = c_[k] * inv;
            acc[k][0] = fmaf(ck, __uint_as_float(P[k] << 16),         acc[k][0]);
            acc[k][1] = fmaf(ck, __uint_as_float(P[k] & 0xffff0000u), acc[k][1]);
        }
#pragma unroll
        for (int k = 0; k < K_; k++) P[k] = Q[k];
    }
}

// reduce acc over the 8 i-positions of each wave; deposit per-wave sums.
// red: [16 waves][160]
static __device__ __forceinline__ void block_reduce(
    float acc[K_][2], float* __restrict__ red, int lane, int wv)
{
#pragma unroll
    for (int k = 0; k < K_; k++)
#pragma unroll
        for (int j = 0; j < 2; j++) {
            float a = acc[k][j];
            a += __shfl_xor(a, 8); a += __shfl_xor(a, 16); a += __shfl_xor(a, 32);
            acc[k][j] = a;
        }
    if (lane < 8) {
#pragma unroll
        for (int k = 0; k < K_; k++)
            *(float2*)&red[wv * 160 + k * 16 + lane * 2] =
                make_float2(acc[k][0], acc[k][1]);
    }
    __syncthreads();
}

// sum the 16 per-wave partials for element t (t < 160)
static __device__ __forceinline__ float sum16(const float* __restrict__ red, int t)
{
    float s = 0.f;
#pragma unroll
    for (int wgi = 0; wgi < 16; wgi++) s += red[wgi * 160 + t];
    return s;
}

// squash for element t<160: 16-lane o-group norm reduce
static __device__ __forceinline__ float squash_v(float s) {
    float n2 = s * s;
    n2 += __shfl_xor(n2, 1); n2 += __shfl_xor(n2, 2);
    n2 += __shfl_xor(n2, 4); n2 += __shfl_xor(n2, 8);
    const float norm = sqrtf(n2);
    return s * (n2 / (1.0f + n2) / (norm + 1e-9f));
}

// ---------------------------------------------------------------------------
// route_all v13: passes 2+3; pass 1 from part[x][k][b][o].
// grid (256), 1024 thr (16 waves, 4/SIMD).
// ---------------------------------------------------------------------------
__global__ __launch_bounds__(1024) void route_all(
    const unsigned short* __restrict__ u, const float* __restrict__ part,
    float* __restrict__ out)
{
    __shared__ float red[16 * 160];
    __shared__ float v_lds[160];
    __shared__ float v1_lds[160];

    const int t    = threadIdx.x;
    const int og   = t & 7, i_l = t >> 3;   // og: o-pair idx, i_l in 0..127
    const int b    = blockIdx.x;
    const int lane = t & 63, wv = t >> 6;   // wv in 0..15

    const char* ubb = (const char*)(u + (size_t)b * K_ * I_ * O_);
    float acc[K_][2];

    // ---- prologue: s1 = sum over the 72 i-blocks; v1 = squash(s1/K) ----
    if (t < 160) {
        const int k = t >> 4, o = t & 15;
        const float* pb = part + ((size_t)k * 256 + b) * O_ + o;
        float s = 0.f;
#pragma unroll
        for (int xb = 0; xb < NX; xb++)
            s += pb[(size_t)xb * BKO];
        float v = squash_v(s * (1.0f / K_));
        v1_lds[t] = v;
        v_lds[t]  = v;
    }
    __syncthreads();

    // ---- pass 2: logits from v1 ----
    sweep(ubb, i_l, og, v_lds, acc);
    block_reduce(acc, red, lane, wv);
    float v12 = 0.f;
    if (t < 160) v12 = v1_lds[t] + squash_v(sum16(red, t));
    __syncthreads();          // all sum16 reads done before v_lds overwrite
    if (t < 160) v_lds[t] = v12;
    __syncthreads();

    // ---- pass 3: logits from v1+v2 (telescoped) ----
    sweep(ubb, i_l, og, v_lds, acc);
    block_reduce(acc, red, lane, wv);
    if (t < 160)
        out[(size_t)b * 160 + t] = squash_v(sum16(red, t));
}

// ---------------------------------------------------------------------------
extern "C" void kernel_launch(void* const* d_in, const int* in_sizes, int n_in,
                              void* d_out, int out_size, void* d_ws, size_t ws_size,
                              hipStream_t stream)
{
    const float* x = (const float*)d_in[0];
    const float* w = (const float*)d_in[1];
    float* outp = (float*)d_out;

    float* part = (float*)d_ws;                          // NX*BKO f32 = 11.8 MB
    unsigned short* u = (unsigned short*)(part + (size_t)NX * BKO);  // 94.4 MB

    uhat_kernel<<<dim3(72, 4, 10), 256, 0, stream>>>(x, w, u, part);
    route_all<<<B_, 1024, 0, stream>>>(u, part, outp);
}